// Round 6
// baseline (258.074 us; speedup 1.0000x reference)
//
#include <hip/hip_runtime.h>
#include <math.h>

// ---------------------------------------------------------------------------
// HierarchicalVAE, MI355X (gfx950), fp32 — R12: one kernel, wide stages,
// light MALL barriers.
// Model (R6..R11 reconciled): wide stage kernels exec in ~2-6us; kernel
// boundaries cost ~15-18us FIXED each (R7 = 9 boundaries = 190us); per-row
// fusion (R6/R11 mid/tail) trades boundaries for per-block all-column weight
// chains (103-137us) — worse. R8/R10 fused attempts failed for separate,
// now-understood reasons: coop launch = +100us fixed; all-uncached activation
// READS = the 200us kernel.
// R12: regular launch, 256 blocks x 512 thr (1/CU, co-resident), R7's wide
// per-stage mappings (2 chunks/block for 512-chunk stages). Activation WRITES
// + barrier counters use agent-scope (MALL) ops; all READS stay cached
// (kernel-start L2 invalidate + first-touch-post-barrier makes this safe —
// same mechanism that made R7's cross-kernel cached reads correct).
// __syncthreads drains vmcnt before the tid0 arrival add -> release without
// L2 flush. Spin has a timeout escape (no hang).
//
// Output layout (flat f32): rendered@0, mu@100352, logvar@108544,
// cp@116736, widths@124928, alphas@125184.
// ---------------------------------------------------------------------------

#define O_MU  100352
#define O_LV  108544
#define O_CP  116736
#define O_WD  124928
#define O_AL  125184

// workspace float offsets
#define W_H1   0        // h1_T  [256][128]
#define W_HE   32768    // he_T  [256][128]
#define W_MUT  65536    // mu_T  [64][128]
#define W_LVT  73728    // lv_T  [64][128]
#define W_D1   81920    // d1_T  [512][128]
#define W_H2   147456   // h2_T  [512][128]
#define W_PN   212992   // pn_T  [28][128]
#define W_R1   216576   // r1_T  [512][128]
#define W_PT   282112   // P_T   [52][128]
#define W_WA   288768   // wa_T  [4][128]
#define W_BAR  289280   // 8 unsigned barrier counters
#define NBLK   256

__device__ __forceinline__ float leaky(float x) { return x >= 0.f ? x : 0.2f * x; }
__device__ __forceinline__ float seluf(float x) {
    const float s = 1.0507009873554805f, a = 1.6732632423543772f;
    return x > 0.f ? s * x : s * (a * expm1f(x));
}
__device__ __forceinline__ float sigm(float x) { return 1.f / (1.f + expf(-x)); }

// agent-scope (device-coherent, MALL) store for cross-block activations
__device__ __forceinline__ void stws(float* p, float v) {
    __hip_atomic_store(p, v, __ATOMIC_RELAXED, __HIP_MEMORY_SCOPE_AGENT);
}

// light phase barrier: all waves' sc1 stores are drained by the vmcnt(0)
// hipcc emits before s_barrier; then tid0 arrives and spins at MALL.
__device__ __forceinline__ void arrive_wait(unsigned* c) {
    __syncthreads();
    if (threadIdx.x == 0) {
        __hip_atomic_fetch_add(c, 1u, __ATOMIC_RELAXED, __HIP_MEMORY_SCOPE_AGENT);
        unsigned tries = 0;
        while (__hip_atomic_load(c, __ATOMIC_RELAXED, __HIP_MEMORY_SCOPE_AGENT) < NBLK) {
            __builtin_amdgcn_s_sleep(4);
            if (++tries > (1u << 16)) break;   // safety escape, never hang
        }
    }
    __syncthreads();
    asm volatile("" ::: "memory");   // keep post-barrier loads below the wait
}

__global__ __launch_bounds__(512)
void vae_flow(const float* __restrict__ x, const float* __restrict__ eps,
              const float* __restrict__ enc_w1, const float* __restrict__ enc_b1,
              const float* __restrict__ enc_w2, const float* __restrict__ enc_b2,
              const float* __restrict__ mu_w, const float* __restrict__ mu_b,
              const float* __restrict__ lv_w, const float* __restrict__ lv_b,
              const float* __restrict__ dec_w1, const float* __restrict__ dec_b1,
              const float* __restrict__ dec_w2, const float* __restrict__ dec_b2,
              const float* __restrict__ cp_w, const float* __restrict__ cp_b,
              const float* __restrict__ ref_w1, const float* __restrict__ ref_b1,
              const float* __restrict__ ref_w2, const float* __restrict__ ref_b2,
              const float* __restrict__ wd_w, const float* __restrict__ wd_b,
              const float* __restrict__ al_w, const float* __restrict__ al_b,
              float* __restrict__ out, float* __restrict__ ws) {
    __shared__ float sPart[1024];           // 8 x 2 x 64 reduce scratch
    __shared__ float sP[56];
    __shared__ float sWA[4];
    __shared__ float sQ[128];

    const int b = blockIdx.x;
    const int tid = threadIdx.x;
    const int lane = tid & 63, ks = tid >> 6;   // 8 K-groups of 64 lanes

    float* const h1T = ws + W_H1;
    float* const heT = ws + W_HE;
    float* const muT = ws + W_MUT;
    float* const lvT = ws + W_LVT;
    float* const d1T = ws + W_D1;
    float* const h2T = ws + W_H2;
    float* const pnT = ws + W_PN;
    float* const r1T = ws + W_R1;
    float* const PT  = ws + W_PT;
    float* const waT = ws + W_WA;
    unsigned* const bar = (unsigned*)(ws + W_BAR);

    // ============ stage 1: enc1 (512 chunks; j=c>>1, h=c&1, slice 98) ==========
    for (int cc = 0; cc < 2; ++cc) {
        const int c = b + cc * 256;
        const int j = c >> 1, h = c & 1;
        const int r = h * 64 + lane;
        const float* __restrict__ xr = x + r * 784;
        const int k0 = ks * 98;
        float acc = 0.f;
#pragma unroll 7
        for (int i = 0; i < 98; i++)
            acc = fmaf(xr[k0 + i], enc_w1[(k0 + i) * 256 + j], acc);
        sPart[ks * 64 + lane] = acc;
        __syncthreads();
        if (tid < 64) {
            float s = enc_b1[j];
#pragma unroll
            for (int q = 0; q < 8; q++) s += sPart[q * 64 + tid];
            stws(h1T + j * 128 + h * 64 + tid, leaky(s));
        }
        __syncthreads();
    }
    arrive_wait(bar + 0);

    // ============ stage 2: enc2 (512 chunks; slice 32) =========================
    for (int cc = 0; cc < 2; ++cc) {
        const int c = b + cc * 256;
        const int j = c >> 1, h = c & 1;
        const int r = h * 64 + lane;
        const int k0 = ks * 32;
        float acc = 0.f;
#pragma unroll 8
        for (int i = 0; i < 32; i++)
            acc = fmaf(h1T[(k0 + i) * 128 + r], enc_w2[(k0 + i) * 256 + j], acc);
        sPart[ks * 64 + lane] = acc;
        __syncthreads();
        if (tid < 64) {
            float s = enc_b2[j];
#pragma unroll
            for (int q = 0; q < 8; q++) s += sPart[q * 64 + tid];
            stws(heT + j * 128 + h * 64 + tid, leaky(s));
        }
        __syncthreads();
    }
    arrive_wait(bar + 1);

    // ============ stage 3: mu|lv (256 chunks; c=b) =============================
    {
        const int meta = b >> 1, h = b & 1;
        const int head = meta >> 6, col = meta & 63;
        const float* __restrict__ w = head ? lv_w : mu_w;
        const int r = h * 64 + lane;
        const int k0 = ks * 32;
        float acc = 0.f;
#pragma unroll 8
        for (int i = 0; i < 32; i++)
            acc = fmaf(heT[(k0 + i) * 128 + r], w[(k0 + i) * 64 + col], acc);
        sPart[ks * 64 + lane] = acc;
        __syncthreads();
        if (tid < 64) {
            float s = (head ? lv_b : mu_b)[col];
#pragma unroll
            for (int q = 0; q < 8; q++) s += sPart[q * 64 + tid];
            const int rr = h * 64 + tid;
            stws((head ? lvT : muT) + col * 128 + rr, s);
            out[(head ? O_LV : O_MU) + rr * 64 + col] = s;
        }
        __syncthreads();
    }
    arrive_wait(bar + 2);

    // ============ stage 4: dec1 (512 chunks; 2 cols, slice 8) ==================
    for (int cc = 0; cc < 2; ++cc) {
        const int c = b + cc * 256;
        const int j0 = (c >> 1) * 2, h = c & 1;
        const int r = h * 64 + lane;
        const int k0 = ks * 8;
        float a0 = 0.f, a1 = 0.f;
#pragma unroll
        for (int i = 0; i < 8; i++) {
            const int k = k0 + i;
            float zv = fmaf(eps[r * 64 + k], expf(0.5f * lvT[k * 128 + r]), muT[k * 128 + r]);
            a0 = fmaf(zv, dec_w1[k * 512 + j0],     a0);
            a1 = fmaf(zv, dec_w1[k * 512 + j0 + 1], a1);
        }
        sPart[ks * 128 + lane] = a0; sPart[ks * 128 + 64 + lane] = a1;
        __syncthreads();
        if (tid < 128) {
            const int ci = tid >> 6, ll = tid & 63;
            float s = dec_b1[j0 + ci];
#pragma unroll
            for (int q = 0; q < 8; q++) s += sPart[q * 128 + ci * 64 + ll];
            stws(d1T + (j0 + ci) * 128 + h * 64 + ll, seluf(s));
        }
        __syncthreads();
    }
    arrive_wait(bar + 3);

    // ============ stage 5: dec2 (512 chunks; 2 cols, slice 64) =================
    for (int cc = 0; cc < 2; ++cc) {
        const int c = b + cc * 256;
        const int j0 = (c >> 1) * 2, h = c & 1;
        const int r = h * 64 + lane;
        const int k0 = ks * 64;
        float a0 = 0.f, a1 = 0.f;
#pragma unroll 4
        for (int i = 0; i < 64; i++) {
            const float v = d1T[(k0 + i) * 128 + r];
            a0 = fmaf(v, dec_w2[(k0 + i) * 512 + j0],     a0);
            a1 = fmaf(v, dec_w2[(k0 + i) * 512 + j0 + 1], a1);
        }
        sPart[ks * 128 + lane] = a0; sPart[ks * 128 + 64 + lane] = a1;
        __syncthreads();
        if (tid < 128) {
            const int ci = tid >> 6, ll = tid & 63;
            float s = dec_b2[j0 + ci];
#pragma unroll
            for (int q = 0; q < 8; q++) s += sPart[q * 128 + ci * 64 + ll];
            stws(h2T + (j0 + ci) * 128 + h * 64 + ll, seluf(s));
        }
        __syncthreads();
    }
    arrive_wait(bar + 4);

    // ============ stage 6: heads (64 chunks; b<64) =============================
    if (b < 64) {
        const int j = b >> 1, h = b & 1;
        const float* __restrict__ w; int ldw, col;
        if (j < 28)      { w = cp_w; ldw = 28; col = j; }
        else if (j < 30) { w = wd_w; ldw = 2;  col = j - 28; }
        else             { w = al_w; ldw = 2;  col = j - 30; }
        const int r = h * 64 + lane;
        const int k0 = ks * 64;
        float acc = 0.f;
#pragma unroll 8
        for (int i = 0; i < 64; i++)
            acc = fmaf(h2T[(k0 + i) * 128 + r], w[(k0 + i) * ldw + col], acc);
        sPart[ks * 64 + lane] = acc;
        __syncthreads();
        if (tid < 64) {
            float s = 0.f;
#pragma unroll
            for (int q = 0; q < 8; q++) s += sPart[q * 64 + tid];
            const int rr = h * 64 + tid;
            if (j < 28) {
                stws(pnT + j * 128 + rr, tanhf(s + cp_b[col]));
            } else if (j < 30) {
                float v = fmaf(sigm(s + wd_b[col]), 2.f, 1.f);
                out[O_WD + rr * 2 + col] = v; stws(waT + col * 128 + rr, v);
            } else {
                float v = sigm(s + al_b[col]);
                out[O_AL + rr * 2 + col] = v; stws(waT + (2 + col) * 128 + rr, v);
            }
        }
        __syncthreads();
    }
    arrive_wait(bar + 5);

    // ============ stage 7: ref1 (512 chunks; 2 cols, slice 12, guard k<92) =====
    for (int cc = 0; cc < 2; ++cc) {
        const int c = b + cc * 256;
        const int j0 = (c >> 1) * 2, h = c & 1;
        const int r = h * 64 + lane;
        float a0 = 0.f, a1 = 0.f;
#pragma unroll
        for (int i = 0; i < 12; i++) {
            const int k = ks * 12 + i;
            if (k < 92) {
                float v = (k < 64)
                    ? fmaf(eps[r * 64 + k], expf(0.5f * lvT[k * 128 + r]), muT[k * 128 + r])
                    : pnT[(k - 64) * 128 + r];
                a0 = fmaf(v, ref_w1[k * 512 + j0],     a0);
                a1 = fmaf(v, ref_w1[k * 512 + j0 + 1], a1);
            }
        }
        sPart[ks * 128 + lane] = a0; sPart[ks * 128 + 64 + lane] = a1;
        __syncthreads();
        if (tid < 128) {
            const int ci = tid >> 6, ll = tid & 63;
            float s = ref_b1[j0 + ci];
#pragma unroll
            for (int q = 0; q < 8; q++) s += sPart[q * 128 + ci * 64 + ll];
            stws(r1T + (j0 + ci) * 128 + h * 64 + ll, seluf(s));
        }
        __syncthreads();
    }
    arrive_wait(bar + 6);

    // ============ stage 8: ref2 (104 chunks; b<104) ============================
    if (b < 104) {
        const int j = b >> 1, h = b & 1;
        const int r = h * 64 + lane;
        const int k0 = ks * 64;
        float acc = 0.f;
#pragma unroll 8
        for (int i = 0; i < 64; i++)
            acc = fmaf(r1T[(k0 + i) * 128 + r], ref_w2[(k0 + i) * 52 + j], acc);
        sPart[ks * 64 + lane] = acc;
        __syncthreads();
        if (tid < 64) {
            float s = ref_b2[j];
#pragma unroll
            for (int q = 0; q < 8; q++) s += sPart[q * 64 + tid];
            stws(PT + j * 128 + h * 64 + tid, fmaf(tanhf(s), 12.f, 14.f));
        }
        __syncthreads();
    }
    arrive_wait(bar + 7);

    // ============ stage 9: raster (256 chunks; row=b>>1, half=b&1) =============
    {
        const int row = b >> 1, half = b & 1;
        if (tid < 52) sP[tid] = PT[tid * 128 + row];
        if (tid >= 64 && tid < 68) sWA[tid - 64] = waT[(tid - 64) * 128 + row];
        __syncthreads();
        if (half == 0 && tid < 64) {
            const int idx = tid, p = idx >> 5, rest = idx & 31;
            const int s = rest >> 3, kk = (rest >> 1) & 3, d = idx & 1;
            out[O_CP + row * 64 + idx] = sP[p * 26 + (3 * s + kk) * 2 + d];
        }
        if (tid < 128) {
            const int idx = tid, p = idx >> 6, s = (idx >> 4) & 3, ti = (idx >> 1) & 7, d = idx & 1;
            const float t = (float)ti / 7.0f, mt = 1.0f - t;
            const float c0 = mt * mt * mt, c1 = 3.f * mt * mt * t;
            const float c2 = 3.f * mt * t * t, c3 = t * t * t;
            const float* base = sP + p * 26 + 6 * s + d;
            sQ[idx] = c0 * base[0] + c1 * base[2] + c2 * base[4] + c3 * base[6];
        }
        __syncthreads();
        const float2* __restrict__ sQ2 = (const float2*)sQ;
        for (int u = tid; u < 1568; u += 512) {
            const int pixel = half * 392 + (u >> 2);
            const int sub = u & 3;
            const int py = pixel / 28, px = pixel - py * 28;
            const float sy = ((float)(2 * py + (sub >> 1)) + 0.5f) * 0.5f;
            const float sx = ((float)(2 * px + (sub & 1)) + 0.5f) * 0.5f;
            float img = 1.0f;
#pragma unroll
            for (int p = 0; p < 2; p++) {
                float dmin2 = 1e30f;
                int cnt = 0;
                float2 cur = sQ2[p * 32];
                bool bp = cur.y > sy;
#pragma unroll
                for (int m = 0; m < 32; m++) {
                    float2 nxt = sQ2[p * 32 + ((m + 1) & 31)];
                    float dx = sx - cur.x;
                    float dy = sy - cur.y;
                    dmin2 = fminf(dmin2, fmaf(dx, dx, dy * dy));
                    bool bn = nxt.y > sy;
                    float den = nxt.y - cur.y + 1e-8f;
                    float lhs = dx * den;
                    float rhs = dy * (nxt.x - cur.x);
                    if ((bp != bn) && ((lhs < rhs) == (den > 0.0f))) cnt++;
                    cur = nxt;
                    bp = bn;
                }
                float dist = sqrtf(dmin2);
                float stroke = fminf(fmaxf(fmaf(sWA[p], 0.5f, 0.5f) - dist, 0.f), 1.f);
                float cov = fmaxf((float)(cnt & 1), stroke);
                img *= fmaf(-sWA[2 + p], cov, 1.0f);
            }
            img += __shfl_xor(img, 1);
            img += __shfl_xor(img, 2);
            if (sub == 0) out[row * 784 + pixel] = 1.0f - 0.25f * img;
        }
    }
}

extern "C" void kernel_launch(void* const* d_in, const int* in_sizes, int n_in,
                              void* d_out, int out_size, void* d_ws, size_t ws_size,
                              hipStream_t stream) {
    const float* x      = (const float*)d_in[0];
    const float* eps    = (const float*)d_in[1];
    const float* enc_w1 = (const float*)d_in[2];
    const float* enc_b1 = (const float*)d_in[3];
    const float* enc_w2 = (const float*)d_in[4];
    const float* enc_b2 = (const float*)d_in[5];
    const float* mu_w   = (const float*)d_in[6];
    const float* mu_b   = (const float*)d_in[7];
    const float* lv_w   = (const float*)d_in[8];
    const float* lv_b   = (const float*)d_in[9];
    const float* dec_w1 = (const float*)d_in[10];
    const float* dec_b1 = (const float*)d_in[11];
    const float* dec_w2 = (const float*)d_in[12];
    const float* dec_b2 = (const float*)d_in[13];
    const float* cp_w   = (const float*)d_in[14];
    const float* cp_b   = (const float*)d_in[15];
    const float* ref_w1 = (const float*)d_in[16];
    const float* ref_b1 = (const float*)d_in[17];
    const float* ref_w2 = (const float*)d_in[18];
    const float* ref_b2 = (const float*)d_in[19];
    const float* wd_w   = (const float*)d_in[20];
    const float* wd_b   = (const float*)d_in[21];
    const float* al_w   = (const float*)d_in[22];
    const float* al_b   = (const float*)d_in[23];

    float* out = (float*)d_out;
    float* ws  = (float*)d_ws;   // needs 289312 floats ≈ 1.16 MB

    // zero the 8 barrier counters (ws is re-poisoned between iterations)
    hipMemsetAsync(ws + W_BAR, 0, 8 * sizeof(unsigned), stream);

    vae_flow<<<256, 512, 0, stream>>>(x, eps, enc_w1, enc_b1, enc_w2, enc_b2,
                                      mu_w, mu_b, lv_w, lv_b, dec_w1, dec_b1,
                                      dec_w2, dec_b2, cp_w, cp_b, ref_w1, ref_b1,
                                      ref_w2, ref_b2, wd_w, wd_b, al_w, al_b,
                                      out, ws);
}